// Round 2
// baseline (654.488 us; speedup 1.0000x reference)
//
#include <hip/hip_runtime.h>

#define NN   100000
#define DIN  1152

// ---- ws layout (fp32): ------------------------------------------------
//  [0     .. 6144)  W0[u][v]  = w1_0[u,v] * inv_in                  (128x48)
//  [6144  .. 8192)  W1[u][v]  = w1_1[u,v] * w2_1[v] * inv_in*inv_h  (128x16)
//  [8192  ..10240)  W2[u][v]  = w1_2[u,v] * w2_2[v] * inv_in*inv_h  (128x16)
//  [10240 ..10256)  W20[v]    = w2_0[v] * inv_h                     (16)
// -----------------------------------------------------------------------

__global__ void __launch_bounds__(256) prep_weights(
    const float* __restrict__ w10, const float* __restrict__ w11,
    const float* __restrict__ w12, const float* __restrict__ w20,
    const float* __restrict__ w21, const float* __restrict__ w22,
    float* __restrict__ ws) {
  int t = blockIdx.x * 256 + threadIdx.x;
  const float inv_in = 0.08838834764831845f;          // 1/sqrt(128)
  const float inv_ih = 0.25f * 0.08838834764831845f;  // 1/sqrt(128)/sqrt(16)
  if (t < 6144) ws[t] = w10[t] * inv_in;
  if (t < 2048) {
    int v = t & 15;
    ws[6144 + t] = w11[t] * w21[v] * inv_ih;
    ws[8192 + t] = w12[t] * w22[v] * inv_ih;
  }
  if (t < 16) ws[10240 + t] = w20[t] * 0.25f;         // 1/sqrt(16)
}

__global__ void __launch_bounds__(256) fused_node_kernel(
    const float* __restrict__ x, const float* __restrict__ ws,
    float* __restrict__ out) {
  const int node = blockIdx.x * 256 + threadIdx.x;
  if (node >= NN) return;

  const float* __restrict__ W0  = ws;           // wave-uniform -> s_load
  const float* __restrict__ W1  = ws + 6144;
  const float* __restrict__ W2  = ws + 8192;
  const float* __restrict__ W20 = ws + 10240;
  const float4* __restrict__ xr =
      reinterpret_cast<const float4*>(x + (size_t)node * DIN);  // row is 16B-aligned

  // ---------------- phase 0: y0 = x0 @ W0 (128 -> 48) ----------------
  float y0[48];
  #pragma unroll
  for (int v = 0; v < 48; ++v) y0[v] = 0.f;

  #pragma unroll 2
  for (int q = 0; q < 32; ++q) {                 // 4 u's per iteration
    float4 d = xr[q];
    const float* w = W0 + q * 192;               // (4q)*48
    #pragma unroll
    for (int v = 0; v < 48; ++v)
      y0[v] = fmaf(d.x, w[v],
              fmaf(d.y, w[48 + v],
              fmaf(d.z, w[96 + v],
              fmaf(d.w, w[144 + v], y0[v]))));
  }

  // ---------------- SiLU + scalar head ----------------
  float o0 = 0.f;
  float g1[16], g2[16];
  #pragma unroll
  for (int v = 0; v < 16; ++v) {
    float t = y0[v];
    o0 = fmaf(t / (1.f + __expf(-t)), W20[v], o0);
  }
  #pragma unroll
  for (int v = 0; v < 16; ++v) { float t = y0[16 + v]; g1[v] = t / (1.f + __expf(-t)); }
  #pragma unroll
  for (int v = 0; v < 16; ++v) { float t = y0[32 + v]; g2[v] = t / (1.f + __expf(-t)); }

  // ---- l=1 path: o1[i] = sum_u x[128+3u+i] * (W1[u,:] . g1) ----
  // elements [128,512) = float4 idx [32,128): 4 u's = 12 elems = 3 float4 per iter
  float o1[3] = {0.f, 0.f, 0.f};
  #pragma unroll 2
  for (int k = 0; k < 32; ++k) {
    float4 a = xr[32 + 3 * k], b = xr[33 + 3 * k], c = xr[34 + 3 * k];
    float e[12] = {a.x, a.y, a.z, a.w, b.x, b.y, b.z, b.w, c.x, c.y, c.z, c.w};
    #pragma unroll
    for (int j = 0; j < 4; ++j) {
      const float* wp = W1 + (4 * k + j) * 16;   // uniform -> s_load
      float tmp = 0.f;
      #pragma unroll
      for (int v = 0; v < 16; ++v) tmp = fmaf(wp[v], g1[v], tmp);
      #pragma unroll
      for (int i = 0; i < 3; ++i) o1[i] = fmaf(e[3 * j + i], tmp, o1[i]);
    }
  }

  // ---- l=2 path: o2[i] = sum_u x[512+5u+i] * (W2[u,:] . g2) ----
  // elements [512,1152) = float4 idx [128,288): 4 u's = 20 elems = 5 float4 per iter
  float o2[5] = {0.f, 0.f, 0.f, 0.f, 0.f};
  #pragma unroll 2
  for (int k = 0; k < 32; ++k) {
    float4 a = xr[128 + 5 * k], b = xr[129 + 5 * k], c = xr[130 + 5 * k],
           d = xr[131 + 5 * k], f = xr[132 + 5 * k];
    float e[20] = {a.x, a.y, a.z, a.w, b.x, b.y, b.z, b.w, c.x, c.y, c.z, c.w,
                   d.x, d.y, d.z, d.w, f.x, f.y, f.z, f.w};
    #pragma unroll
    for (int j = 0; j < 4; ++j) {
      const float* wp = W2 + (4 * k + j) * 16;   // uniform -> s_load
      float tmp = 0.f;
      #pragma unroll
      for (int v = 0; v < 16; ++v) tmp = fmaf(wp[v], g2[v], tmp);
      #pragma unroll
      for (int i = 0; i < 5; ++i) o2[i] = fmaf(e[5 * j + i], tmp, o2[i]);
    }
  }

  // ---------------- store 9 outputs ----------------
  float* po = out + (size_t)node * 9;
  po[0] = o0;
  #pragma unroll
  for (int i = 0; i < 3; ++i) po[1 + i] = o1[i];
  #pragma unroll
  for (int i = 0; i < 5; ++i) po[4 + i] = o2[i];
}

extern "C" void kernel_launch(void* const* d_in, const int* in_sizes, int n_in,
                              void* d_out, int out_size, void* d_ws, size_t ws_size,
                              hipStream_t stream) {
  const float* x   = (const float*)d_in[0];
  const float* w10 = (const float*)d_in[1];
  const float* w11 = (const float*)d_in[2];
  const float* w12 = (const float*)d_in[3];
  const float* w20 = (const float*)d_in[4];
  const float* w21 = (const float*)d_in[5];
  const float* w22 = (const float*)d_in[6];
  float* ws = (float*)d_ws;

  prep_weights<<<24, 256, 0, stream>>>(w10, w11, w12, w20, w21, w22, ws);

  int blocks = (NN + 255) / 256;   // 391
  fused_node_kernel<<<blocks, 256, 0, stream>>>(x, ws, (float*)d_out);
}